// Round 1
// baseline (817.870 us; speedup 1.0000x reference)
//
#include <hip/hip_runtime.h>
#include <hip/hip_bf16.h>

typedef __attribute__((ext_vector_type(8))) short short8;
typedef __attribute__((ext_vector_type(4))) short short4v;
typedef __attribute__((ext_vector_type(4))) float floatx4;

#define NEGVAL (-4294967296.0f)

__device__ __forceinline__ short f2bf(float f) {
    union { float f; unsigned u; } v; v.f = f;
    unsigned r = v.u + 0x7fffu + ((v.u >> 16) & 1u);   // RNE
    return (short)(r >> 16);
}

// ---------------------------------------------------------------------------
// Kernel 1: QKV projection. C[16384,1536] = x[16384,512] @ [wq|wk|wv] + bias
// Output scattered to head-major bf16: ws[(h*16+b)*1024 + s][d]
// ---------------------------------------------------------------------------
__global__ __launch_bounds__(256) void qkv_kernel(
    const float* __restrict__ x,
    const float* __restrict__ wq, const float* __restrict__ bq,
    const float* __restrict__ wk, const float* __restrict__ bk,
    const float* __restrict__ wv, const float* __restrict__ bv,
    short* __restrict__ qws, short* __restrict__ kws, short* __restrict__ vws)
{
    __shared__ __align__(16) short lA[128 * 72];   // [m][k] pitch 72
    __shared__ __align__(16) short lB[128 * 72];   // [n][k] pitch 72 (transposed W)

    const int tid  = threadIdx.x;
    const int wave = tid >> 6, lane = tid & 63;
    const int g = lane >> 4, l16 = lane & 15;
    const int m0 = blockIdx.x * 128;
    const int c0 = blockIdx.y * 128;             // global col 0..1535
    const int wsel = c0 >> 9;
    const int cmat = c0 & 511;                   // col base within one matrix
    const float* W    = (wsel == 0) ? wq : (wsel == 1) ? wk : wv;
    const float* bias = (wsel == 0) ? bq : (wsel == 1) ? bk : bv;
    short* dst        = (wsel == 0) ? qws : (wsel == 1) ? kws : vws;

    floatx4 acc[4][4];
    #pragma unroll
    for (int i = 0; i < 4; i++)
        #pragma unroll
        for (int j = 0; j < 4; j++) acc[i][j] = (floatx4){0.f, 0.f, 0.f, 0.f};

    const int wm = (wave & 1) * 64, wn = (wave >> 1) * 64;

    for (int k0 = 0; k0 < 512; k0 += 32) {
        // stage A: 128x32 fp32 -> bf16
        #pragma unroll
        for (int it = 0; it < 4; ++it) {
            int u = tid + (it << 8);                 // 1024 float4 units
            int row = u >> 3, cs = (u & 7) * 4;
            const float4 a = *(const float4*)&x[(size_t)(m0 + row) * 512 + k0 + cs];
            short4v s4;
            s4[0] = f2bf(a.x); s4[1] = f2bf(a.y); s4[2] = f2bf(a.z); s4[3] = f2bf(a.w);
            *(short4v*)&lA[row * 72 + cs] = s4;
        }
        // stage B transposed: lB[n][k]
        #pragma unroll
        for (int it = 0; it < 4; ++it) {
            int u = tid + (it << 8);
            int d = u >> 5, cs = (u & 31) * 4;
            const float4 b = *(const float4*)&W[(size_t)(k0 + d) * 512 + cmat + cs];
            lB[(cs + 0) * 72 + d] = f2bf(b.x);
            lB[(cs + 1) * 72 + d] = f2bf(b.y);
            lB[(cs + 2) * 72 + d] = f2bf(b.z);
            lB[(cs + 3) * 72 + d] = f2bf(b.w);
        }
        __syncthreads();

        short8 af[4], bf[4];
        #pragma unroll
        for (int i = 0; i < 4; i++)
            af[i] = *(short8*)&lA[(wm + i * 16 + l16) * 72 + (g << 3)];
        #pragma unroll
        for (int j = 0; j < 4; j++)
            bf[j] = *(short8*)&lB[(wn + j * 16 + l16) * 72 + (g << 3)];
        #pragma unroll
        for (int i = 0; i < 4; i++)
            #pragma unroll
            for (int j = 0; j < 4; j++)
                acc[i][j] = __builtin_amdgcn_mfma_f32_16x16x32_bf16(af[i], bf[j], acc[i][j], 0, 0, 0);
        __syncthreads();
    }

    // epilogue: bias + scatter to head-major bf16
    #pragma unroll
    for (int j = 0; j < 4; j++) {
        int cb = cmat + wn + j * 16 + l16;          // col within mat 0..511
        float bv_ = bias[cb];
        int h = cb >> 6, qd = cb & 63;
        #pragma unroll
        for (int i = 0; i < 4; i++) {
            #pragma unroll
            for (int r = 0; r < 4; r++) {
                int m = m0 + wm + i * 16 + (g << 2) + r;
                int b = m >> 10, s = m & 1023;
                float v = acc[i][j][r] + bv_;
                dst[(((size_t)((h << 4) + b) << 10) + s) * 64 + qd] = f2bf(v);
            }
        }
    }
}

// ---------------------------------------------------------------------------
// Kernel 2: flash-style attention per (row-tile, n). Writes raw score (fp32)
// and attn heads (bf16, layout (B,S,H*V)).
// ---------------------------------------------------------------------------
__global__ __launch_bounds__(256) void attn_kernel(
    const short* __restrict__ qws, const short* __restrict__ kws,
    const short* __restrict__ vws, const int* __restrict__ pm,
    float* __restrict__ raw, short* __restrict__ attnws)
{
    __shared__ __align__(16) short lK[64 * 72];       // K chunk [t][d]
    __shared__ __align__(16) short lVt[64 * 72];      // V chunk transposed [v][t]
    __shared__ __align__(16) short lP[4][16 * 72];    // per-wave P [row][t]
    __shared__ float lMask[1024];

    const int tid  = threadIdx.x;
    const int wave = tid >> 6, lane = tid & 63;
    const int g = lane >> 4, l16 = lane & 15;
    const int bx = blockIdx.x;      // row tile 0..15
    const int n  = blockIdx.y;      // head-major batch-head 0..127
    const int mb = n >> 3;          // faithful index-mismatch: mask batch = n // H

    for (int i = tid; i < 1024; i += 256) lMask[i] = (float)pm[(mb << 10) + i];

    // Q fragments (held for whole block)
    const int srow = (bx << 6) + (wave << 4) + l16;
    const size_t qbase = (((size_t)n << 10) + srow) * 64;
    short8 qf0 = *(const short8*)&qws[qbase + (g << 3)];
    short8 qf1 = *(const short8*)&qws[qbase + 32 + (g << 3)];

    float m_r[4], l_r[4];
    floatx4 Of[4];
    #pragma unroll
    for (int r = 0; r < 4; r++) { m_r[r] = -INFINITY; l_r[r] = 0.f; }
    #pragma unroll
    for (int v = 0; v < 4; v++) Of[v] = (floatx4){0.f, 0.f, 0.f, 0.f};

    float* rawn = raw + ((size_t)n << 20);
    const int rowbase = (bx << 6) + (wave << 4) + (g << 2);

    for (int c = 0; c < 16; ++c) {
        const int tc = c << 6;
        // stage K (row-major) and V (transposed)
        #pragma unroll
        for (int it = 0; it < 2; ++it) {
            int u = tid + (it << 8);                 // 512 units of 8 bf16
            int trow = u >> 3, seg = (u & 7) << 3;
            const size_t gaddr = (((size_t)n << 10) + tc + trow) * 64 + seg;
            *(uint4*)&lK[trow * 72 + seg] = *(const uint4*)&kws[gaddr];
            union { uint4 u4; short s8[8]; } vv;
            vv.u4 = *(const uint4*)&vws[gaddr];
            #pragma unroll
            for (int j = 0; j < 8; j++) lVt[(seg + j) * 72 + trow] = vv.s8[j];
        }
        __syncthreads();

        // QK^T for this wave's 16 rows x 64 cols
        floatx4 sc[4];
        #pragma unroll
        for (int nt = 0; nt < 4; ++nt) {
            floatx4 a = (floatx4){0.f, 0.f, 0.f, 0.f};
            short8 b0 = *(short8*)&lK[(nt * 16 + l16) * 72 + (g << 3)];
            short8 b1 = *(short8*)&lK[(nt * 16 + l16) * 72 + 32 + (g << 3)];
            a = __builtin_amdgcn_mfma_f32_16x16x32_bf16(qf0, b0, a, 0, 0, 0);
            a = __builtin_amdgcn_mfma_f32_16x16x32_bf16(qf1, b1, a, 0, 0, 0);
            sc[nt] = a;
        }

        // scale, raw write, mask, online softmax
        float p[4][4];
        float cmax[4] = {-INFINITY, -INFINITY, -INFINITY, -INFINITY};
        #pragma unroll
        for (int nt = 0; nt < 4; ++nt) {
            int col = tc + nt * 16 + l16;
            float mk = lMask[col];
            #pragma unroll
            for (int r = 0; r < 4; r++) {
                float v = sc[nt][r] * 0.125f;
                __builtin_nontemporal_store(v, &rawn[((size_t)(rowbase + r) << 10) + col]);
                float mv = (mk != 0.f) ? v : NEGVAL;
                p[nt][r] = mv;
                cmax[r] = fmaxf(cmax[r], mv);
            }
        }
        #pragma unroll
        for (int off = 1; off < 16; off <<= 1) {
            #pragma unroll
            for (int r = 0; r < 4; r++) cmax[r] = fmaxf(cmax[r], __shfl_xor(cmax[r], off));
        }
        float alpha[4], rs[4];
        #pragma unroll
        for (int r = 0; r < 4; r++) {
            float mn = fmaxf(m_r[r], cmax[r]);
            alpha[r] = __expf(m_r[r] - mn);
            m_r[r] = mn;
            rs[r] = 0.f;
        }
        #pragma unroll
        for (int nt = 0; nt < 4; ++nt) {
            #pragma unroll
            for (int r = 0; r < 4; r++) {
                float e = __expf(p[nt][r] - m_r[r]);
                p[nt][r] = e;
                rs[r] += e;
            }
        }
        #pragma unroll
        for (int off = 1; off < 16; off <<= 1) {
            #pragma unroll
            for (int r = 0; r < 4; r++) rs[r] += __shfl_xor(rs[r], off);
        }
        #pragma unroll
        for (int r = 0; r < 4; r++) l_r[r] = l_r[r] * alpha[r] + rs[r];
        #pragma unroll
        for (int v = 0; v < 4; v++)
            #pragma unroll
            for (int r = 0; r < 4; r++) Of[v][r] *= alpha[r];

        // P -> LDS (C-layout -> A-layout transform)
        #pragma unroll
        for (int nt = 0; nt < 4; ++nt)
            #pragma unroll
            for (int r = 0; r < 4; r++)
                lP[wave][((g << 2) + r) * 72 + nt * 16 + l16] = f2bf(p[nt][r]);
        __syncthreads();

        // PV accumulate
        #pragma unroll
        for (int ks = 0; ks < 2; ++ks) {
            short8 pa = *(short8*)&lP[wave][l16 * 72 + ks * 32 + (g << 3)];
            #pragma unroll
            for (int v = 0; v < 4; v++) {
                short8 vb = *(short8*)&lVt[(v * 16 + l16) * 72 + ks * 32 + (g << 3)];
                Of[v] = __builtin_amdgcn_mfma_f32_16x16x32_bf16(pa, vb, Of[v], 0, 0, 0);
            }
        }
        __syncthreads();
    }

    // epilogue: O / l, store heads layout (B,S,H*V) bf16
    const int h = n >> 4, b = n & 15;
    #pragma unroll
    for (int r = 0; r < 4; r++) {
        int s = (bx << 6) + (wave << 4) + (g << 2) + r;
        float inv = 1.f / l_r[r];
        size_t base = ((size_t)((b << 10) + s)) * 512 + (h << 6);
        #pragma unroll
        for (int v = 0; v < 4; v++)
            attnws[base + v * 16 + l16] = f2bf(Of[v][r] * inv);
    }
}

// ---------------------------------------------------------------------------
// Kernel 3: out = heads[16384,512] @ wo[512,512] + bo, fp32 out
// ---------------------------------------------------------------------------
__global__ __launch_bounds__(256) void outproj_kernel(
    const short* __restrict__ attnws, const float* __restrict__ wo,
    const float* __restrict__ bo, float* __restrict__ out)
{
    __shared__ __align__(16) short lA[128 * 72];
    __shared__ __align__(16) short lB[128 * 72];

    const int tid  = threadIdx.x;
    const int wave = tid >> 6, lane = tid & 63;
    const int g = lane >> 4, l16 = lane & 15;
    const int m0 = blockIdx.x * 128;
    const int c0 = blockIdx.y * 128;

    floatx4 acc[4][4];
    #pragma unroll
    for (int i = 0; i < 4; i++)
        #pragma unroll
        for (int j = 0; j < 4; j++) acc[i][j] = (floatx4){0.f, 0.f, 0.f, 0.f};

    const int wm = (wave & 1) * 64, wn = (wave >> 1) * 64;

    for (int k0 = 0; k0 < 512; k0 += 32) {
        #pragma unroll
        for (int it = 0; it < 2; ++it) {
            int u = tid + (it << 8);                 // 512 units of 8 bf16
            int row = u >> 2, seg = (u & 3) << 3;
            *(uint4*)&lA[row * 72 + seg] =
                *(const uint4*)&attnws[(size_t)(m0 + row) * 512 + k0 + seg];
        }
        #pragma unroll
        for (int it = 0; it < 4; ++it) {
            int u = tid + (it << 8);
            int d = u >> 5, cs = (u & 31) * 4;
            const float4 b = *(const float4*)&wo[(size_t)(k0 + d) * 512 + c0 + cs];
            lB[(cs + 0) * 72 + d] = f2bf(b.x);
            lB[(cs + 1) * 72 + d] = f2bf(b.y);
            lB[(cs + 2) * 72 + d] = f2bf(b.z);
            lB[(cs + 3) * 72 + d] = f2bf(b.w);
        }
        __syncthreads();

        short8 af[4], bf[4];
        #pragma unroll
        for (int i = 0; i < 4; i++)
            af[i] = *(short8*)&lA[(wm + i * 16 + l16) * 72 + (g << 3)];
        #pragma unroll
        for (int j = 0; j < 4; j++)
            bf[j] = *(short8*)&lB[(wn + j * 16 + l16) * 72 + (g << 3)];
        #pragma unroll
        for (int i = 0; i < 4; i++)
            #pragma unroll
            for (int j = 0; j < 4; j++)
                acc[i][j] = __builtin_amdgcn_mfma_f32_16x16x32_bf16(af[i], bf[j], acc[i][j], 0, 0, 0);
        __syncthreads();
    }

    #pragma unroll
    for (int j = 0; j < 4; j++) {
        int cg = c0 + wn + j * 16 + l16;
        float bb = bo[cg];
        #pragma unroll
        for (int i = 0; i < 4; i++) {
            #pragma unroll
            for (int r = 0; r < 4; r++) {
                int m = m0 + wm + i * 16 + (g << 2) + r;
                out[(size_t)m * 512 + cg] = acc[i][j][r] + bb;
            }
        }
    }
}

// ---------------------------------------------------------------------------
extern "C" void kernel_launch(void* const* d_in, const int* in_sizes, int n_in,
                              void* d_out, int out_size, void* d_ws, size_t ws_size,
                              hipStream_t stream) {
    const float* x  = (const float*)d_in[0];
    const int*   pm = (const int*)d_in[1];
    const float* wq = (const float*)d_in[2];
    const float* bq = (const float*)d_in[3];
    const float* wk = (const float*)d_in[4];
    const float* bk = (const float*)d_in[5];
    const float* wv = (const float*)d_in[6];
    const float* bv = (const float*)d_in[7];
    const float* wo = (const float*)d_in[8];
    const float* bo = (const float*)d_in[9];

    float* out = (float*)d_out;
    float* raw = out + (size_t)16 * 1024 * 512;       // raw_score after out

    short* qws    = (short*)d_ws;                     // 16 MB each, head-major bf16
    short* kws    = qws + (size_t)128 * 1024 * 64;
    short* vws    = kws + (size_t)128 * 1024 * 64;
    short* attnws = vws + (size_t)128 * 1024 * 64;    // heads (B,S,H*V) bf16

    qkv_kernel<<<dim3(128, 12), 256, 0, stream>>>(x, wq, bq, wk, bk, wv, bv, qws, kws, vws);
    attn_kernel<<<dim3(16, 128), 256, 0, stream>>>(qws, kws, vws, pm, raw, attnws);
    outproj_kernel<<<dim3(128, 4), 256, 0, stream>>>(attnws, wo, bo, out);
}